// Round 3
// baseline (414.037 us; speedup 1.0000x reference)
//
#include <hip/hip_runtime.h>
#include <math.h>

#define BN_EPS 1e-5f

typedef short bf16x8 __attribute__((ext_vector_type(8)));
typedef float f32x4 __attribute__((ext_vector_type(4)));
typedef unsigned short ushort8v __attribute__((ext_vector_type(8)));
typedef unsigned int uint;
typedef unsigned short ushort;

__device__ inline ushort f2bf(float f) {           // RNE float->bf16
    uint u = __float_as_uint(f);
    uint r = u + 0x7FFFu + ((u >> 16) & 1u);
    return (ushort)(r >> 16);
}
__device__ inline float bf2f(ushort u) { return __uint_as_float(((uint)u) << 16); }

// ---------------------------------------------------------------------------
// pooled[bc] = mean over 128x128 of in[bc][:][:]   (fp32 NCHW input)
// ---------------------------------------------------------------------------
__global__ void pool_kernel(const float* __restrict__ in, float* __restrict__ pooled) {
    const int bc = blockIdx.x;
    const float* p = in + (size_t)bc * (128 * 128);
    float s = 0.f;
    for (int i = threadIdx.x; i < 128 * 128; i += 256) s += p[i];
    for (int off = 32; off > 0; off >>= 1) s += __shfl_down(s, off);
    __shared__ float ls[4];
    const int lane = threadIdx.x & 63, wv = threadIdx.x >> 6;
    if (lane == 0) ls[wv] = s;
    __syncthreads();
    if (threadIdx.x == 0) pooled[bc] = (ls[0] + ls[1] + ls[2] + ls[3]) * (1.f / 16384.f);
}

// ---------------------------------------------------------------------------
// rw[b*3+e] = sigmoid(dot(pooled[b], fc_w[e]) + fc_b[e])
// ---------------------------------------------------------------------------
__global__ void route_kernel(const float* __restrict__ pooled,
                             const float* __restrict__ fc_w,
                             const float* __restrict__ fc_b,
                             float* __restrict__ rw, int C) {
    const int idx = threadIdx.x;
    if (idx < 16 * 3) {
        const int b = idx / 3, e = idx % 3;
        float s = fc_b[e];
        for (int c = 0; c < C; ++c) s += pooled[b * C + c] * fc_w[e * C + c];
        rw[idx] = 1.f / (1.f + expf(-s));
    }
}

// ---------------------------------------------------------------------------
// Per-channel scale/shift for both BN layers: y = acc*sc + sh, then ReLU.
// ---------------------------------------------------------------------------
__global__ void scsh_kernel(const float* b1, const float* g1, const float* bb1,
                            const float* m1, const float* v1,
                            const float* b2, const float* g2, const float* bb2,
                            const float* m2, const float* v2,
                            float* scsh1, float* scsh2) {
    int t = threadIdx.x;
    if (t < 128) {
        float sc = g1[t] * rsqrtf(v1[t] + BN_EPS);
        scsh1[t] = sc;
        scsh1[128 + t] = (b1[t] - m1[t]) * sc + bb1[t];
    } else {
        int c = t - 128;
        float sc = g2[c] * rsqrtf(v2[c] + BN_EPS);
        scsh2[c] = sc;
        scsh2[128 + c] = (b2[c] - m2[c]) * sc + bb2[c];
    }
}

// ---------------------------------------------------------------------------
// Mixed weights: wmix[b][tap][co][ci] (bf16) = sum_e rw[b,e] * w[e][co][ci][tap]
// ---------------------------------------------------------------------------
template <int CIN>
__global__ void mix_kernel(const float* __restrict__ w, const float* __restrict__ rw,
                           ushort* __restrict__ wmix) {
    const int co = blockIdx.x;  // 0..127
    for (int b = 0; b < 16; ++b) {
        const float r0 = rw[b * 3 + 0], r1 = rw[b * 3 + 1], r2 = rw[b * 3 + 2];
        for (int idx = threadIdx.x; idx < CIN * 9; idx += 256) {
            const int ci = idx & (CIN - 1);
            const int tap = idx / CIN;
            const size_t o = ((size_t)co * CIN + ci) * 9 + tap;
            const float m = r0 * w[o]
                          + r1 * w[o + (size_t)128 * CIN * 9]
                          + r2 * w[o + (size_t)2 * 128 * CIN * 9];
            wmix[(((size_t)b * 9 + tap) * 128 + co) * CIN + ci] = f2bf(m);
        }
    }
}

// ---------------------------------------------------------------------------
// x fp32 NCHW [16][64][128][128] -> xT bf16 NHWC [16][128*128][64]
// ---------------------------------------------------------------------------
__global__ void nchw_to_nhwc_kernel(const float* __restrict__ x, ushort* __restrict__ xT) {
    __shared__ float t[64][65];
    const int b = blockIdx.y;
    const int p0 = blockIdx.x * 64;
    const int tid = threadIdx.x;
#pragma unroll
    for (int it = 0; it < 16; ++it) {
        const int idx = it * 256 + tid;
        const int ci = idx >> 6, p = idx & 63;
        t[ci][p] = x[((size_t)b * 64 + ci) * 16384 + p0 + p];
    }
    __syncthreads();
#pragma unroll
    for (int it = 0; it < 2; ++it) {
        const int p = it * 32 + (tid >> 3);
        const int c0 = (tid & 7) * 8;
        ushort8v u;
#pragma unroll
        for (int j = 0; j < 8; ++j) u[j] = f2bf(t[c0 + j][p]);
        *(ushort8v*)&xT[((size_t)b * 16384 + p0 + p) * 64 + c0] = u;
    }
}

// ---------------------------------------------------------------------------
// Pooling of hT (bf16 NHWC, Cout=128)
// ---------------------------------------------------------------------------
__global__ void pool2a_kernel(const ushort* __restrict__ hT, float* __restrict__ part) {
    const int b = blockIdx.x, s = blockIdx.y;  // (16, 64)
    const int c2 = threadIdx.x & 63;
    const int g = threadIdx.x >> 6;
    float s0 = 0.f, s1 = 0.f;
    const ushort* base = hT + ((size_t)b * 16384 + s * 256 + g * 64) * 128 + c2 * 2;
    for (int i = 0; i < 64; ++i) {
        const uint v = *(const uint*)(base + (size_t)i * 128);
        s0 += bf2f((ushort)(v & 0xffffu));
        s1 += bf2f((ushort)(v >> 16));
    }
    __shared__ float sp[4][128];
    sp[g][c2 * 2] = s0;
    sp[g][c2 * 2 + 1] = s1;
    __syncthreads();
    if (threadIdx.x < 128) {
        const int c = threadIdx.x;
        part[((size_t)b * 64 + s) * 128 + c] = sp[0][c] + sp[1][c] + sp[2][c] + sp[3][c];
    }
}

__global__ void pool2b_route2_kernel(const float* __restrict__ part,
                                     const float* __restrict__ fcw,
                                     const float* __restrict__ fcb,
                                     float* __restrict__ rw2) {
    const int b = blockIdx.x;  // 16 blocks, 128 threads
    const int c = threadIdx.x;
    float s = 0.f;
    for (int k = 0; k < 64; ++k) s += part[((size_t)b * 64 + k) * 128 + c];
    __shared__ float sp[128];
    sp[c] = s * (1.f / 16384.f);
    __syncthreads();
    if (c < 3) {
        float d = fcb[c];
        for (int k = 0; k < 128; ++k) d += sp[k] * fcw[c * 128 + k];
        rw2[b * 3 + c] = 1.f / (1.f + expf(-d));
    }
}

// ---------------------------------------------------------------------------
// MFMA implicit-GEMM conv3x3(pad1) + fused bias/BN/ReLU. v3:
//  - 512 thr = 8 waves (2 co-halves x 4 px-quarters), tile 128co x 256px (2 rows)
//  - halo [4 rows][144 cols][32 ci] double-buffered (2 x 36,864 B LDS)
//  - stage issued between tap 3 and tap 4 of current chunk; single barrier/chunk
//  - ci-group XOR swizzle (g ^ (c>>1)&3), applied on pre-swizzled global source
//    AND on the ds_read address -> conflict-free B-fragment reads
//  - bijective XCD-chunked block swizzle: each XCD owns 2 whole images
// ---------------------------------------------------------------------------
template <int CIN, bool TO_BF16>
__global__ __launch_bounds__(512, 4)
void conv_mfma2_kernel(const ushort* __restrict__ xT, const ushort* __restrict__ wmix,
                       const float* __restrict__ scsh,
                       float* __restrict__ outf, ushort* __restrict__ outh,
                       const ushort* __restrict__ zp) {
    constexpr int NCC = CIN / 32;
    __shared__ short lds[2][4 * 144 * 32];  // 2 x 36,864 B

    const int g0 = blockIdx.x;
    const int w = ((g0 & 7) << 7) | (g0 >> 3);  // 1024 wgs: 128 consecutive per XCD
    const int b = w >> 6;
    const int rt = w & 63;                      // row-pair tile: output rows rt*2, rt*2+1

    const int tid = threadIdx.x;
    const int lane = tid & 63, wid = tid >> 6;
    const int wm = wid >> 2, wn = wid & 3;
    const int l15 = lane & 15, lg = lane >> 4;

    f32x4 acc[4][4];
#pragma unroll
    for (int i = 0; i < 4; ++i)
#pragma unroll
        for (int j = 0; j < 4; ++j) acc[i][j] = {0.f, 0.f, 0.f, 0.f};

    const ushort* xTb = xT + (size_t)b * 16384 * CIN;
    const ushort* wb = wmix + (size_t)b * 9 * 128 * CIN;

    int prow[4], pcol[4];
#pragma unroll
    for (int nf = 0; nf < 4; ++nf) {
        const int px = wn * 64 + nf * 16 + l15;
        prow[nf] = px >> 7;
        pcol[nf] = px & 127;
    }

    // ---- staging: 36 wave-instrs of 1KB; slot s=(row*576 + c*4 + g), source
    // ci-group pre-swizzled so the swizzled ds_read finds linear data ----
    auto stage = [&](int bufi, int cc) {
        const int ci0 = cc * 32;
#pragma unroll
        for (int u = 0; u < 5; ++u) {
            const int j = wid + u * 8;
            if (j >= 36) break;
            const int s = j * 64 + lane;
            const int row = s / 576;
            const int rem = s - row * 576;
            const int c = rem >> 2;
            const int g = rem & 3;
            const int gs = g ^ ((c >> 1) & 3);
            const int hg = rt * 2 - 1 + row;
            const int wg = c - 1;
            const ushort* src = zp;
            if ((unsigned)hg < 128u && (unsigned)wg < 128u)
                src = xTb + ((size_t)(hg * 128 + wg)) * CIN + ci0 + gs * 8;
            __builtin_amdgcn_global_load_lds(
                (const __attribute__((address_space(1))) void*)src,
                (__attribute__((address_space(3))) void*)&lds[bufi][(size_t)j * 512],
                16, 0, 0);
        }
    };

    auto taps = [&](int bufi, int cc, int t0, int t1) {
        const int ci0 = cc * 32;
#pragma unroll
        for (int tap = t0; tap < t1; ++tap) {
            const int dy = tap / 3, dx = tap - dy * 3;
            bf16x8 af[4];
#pragma unroll
            for (int mf = 0; mf < 4; ++mf) {
                const int co = wm * 64 + mf * 16 + l15;
                af[mf] = *(const bf16x8*)&wb[((size_t)tap * 128 + co) * CIN + ci0 + lg * 8];
            }
#pragma unroll
            for (int nf = 0; nf < 4; ++nf) {
                const int c = pcol[nf] + dx;
                const int slot = (prow[nf] + dy) * 576 + c * 4 + (lg ^ ((c >> 1) & 3));
                const bf16x8 bv = *(const bf16x8*)&lds[bufi][(size_t)slot * 8];
#pragma unroll
                for (int mf = 0; mf < 4; ++mf)
                    acc[mf][nf] = __builtin_amdgcn_mfma_f32_16x16x32_bf16(
                        af[mf], bv, acc[mf][nf], 0, 0, 0);
            }
        }
    };

    stage(0, 0);
    asm volatile("s_waitcnt vmcnt(0)" ::: "memory");
    __syncthreads();

    for (int cc = 0; cc < NCC; ++cc) {
        const int cur = cc & 1;
        taps(cur, cc, 0, 4);
        if (cc + 1 < NCC) stage(cur ^ 1, cc + 1);
        __builtin_amdgcn_sched_barrier(0);
        taps(cur, cc, 4, 9);
        if (cc + 1 < NCC) {
            // staging loads were issued before taps 4-8's weight loads; the
            // compiler's waits on those already drained them -> cheap.
            asm volatile("s_waitcnt vmcnt(0)" ::: "memory");
            __syncthreads();
        }
    }

    // ---- epilogue: y = relu(acc*sc + sh) ----
#pragma unroll
    for (int mf = 0; mf < 4; ++mf) {
        const int co0 = wm * 64 + mf * 16 + lg * 4;
        const f32x4 sc = *(const f32x4*)&scsh[co0];
        const f32x4 sh = *(const f32x4*)&scsh[128 + co0];
#pragma unroll
        for (int nf = 0; nf < 4; ++nf) {
            const int px = wn * 64 + nf * 16 + l15;
            float v[4];
#pragma unroll
            for (int r = 0; r < 4; ++r) {
                float y = fmaf(acc[mf][nf][r], sc[r], sh[r]);
                v[r] = y > 0.f ? y : 0.f;
            }
            if (TO_BF16) {
                uint2 pk;
                pk.x = (uint)f2bf(v[0]) | ((uint)f2bf(v[1]) << 16);
                pk.y = (uint)f2bf(v[2]) | ((uint)f2bf(v[3]) << 16);
                *(uint2*)&outh[((size_t)b * 16384 + rt * 256 + px) * 128 + co0] = pk;
            } else {
#pragma unroll
                for (int r = 0; r < 4; ++r)
                    outf[((size_t)(b * 128 + co0 + r)) * 16384 + rt * 256 + px] = v[r];
            }
        }
    }
}

// ---------------------------------------------------------------------------
extern "C" void kernel_launch(void* const* d_in, const int* in_sizes, int n_in,
                              void* d_out, int out_size, void* d_ws, size_t ws_size,
                              hipStream_t stream) {
    const float* x     = (const float*)d_in[0];
    const float* w1    = (const float*)d_in[1];
    const float* b1    = (const float*)d_in[2];
    const float* fc1_w = (const float*)d_in[3];
    const float* fc1_b = (const float*)d_in[4];
    const float* bn1g  = (const float*)d_in[5];
    const float* bn1b  = (const float*)d_in[6];
    const float* bn1m  = (const float*)d_in[7];
    const float* bn1v  = (const float*)d_in[8];
    const float* w2    = (const float*)d_in[9];
    const float* b2    = (const float*)d_in[10];
    const float* fc2_w = (const float*)d_in[11];
    const float* fc2_b = (const float*)d_in[12];
    const float* bn2g  = (const float*)d_in[13];
    const float* bn2b  = (const float*)d_in[14];
    const float* bn2m  = (const float*)d_in[15];
    const float* bn2v  = (const float*)d_in[16];

    float* out = (float*)d_out;
    char* ws = (char*)d_ws;

    // workspace layout (bytes)
    ushort* hT    = (ushort*)(ws + 0);            //  67,108,864 B
    ushort* xT    = (ushort*)(ws + 67108864);     //  33,554,432 B
    ushort* wmix1 = (ushort*)(ws + 100663296);    //   2,359,296 B
    ushort* wmix2 = (ushort*)(ws + 103022592);    //   4,718,592 B
    float*  part  = (float*) (ws + 107741184);    //     524,288 B
    float*  pool1 = (float*) (ws + 108265472);    //       4,096 B
    float*  rw1   = (float*) (ws + 108269568);    //         192 B
    float*  rw2   = (float*) (ws + 108269760);    //         192 B
    float*  scsh1 = (float*) (ws + 108269952);    //       1,024 B
    float*  scsh2 = (float*) (ws + 108270976);    //       1,024 B
    ushort* zp    = (ushort*)(ws + 108272000);    //          64 B (zero page)

    hipMemsetAsync(zp, 0, 64, stream);

    scsh_kernel<<<1, 256, 0, stream>>>(b1, bn1g, bn1b, bn1m, bn1v,
                                       b2, bn2g, bn2b, bn2m, bn2v, scsh1, scsh2);

    // ---- layer 1 ----
    pool_kernel<<<16 * 64, 256, 0, stream>>>(x, pool1);
    route_kernel<<<1, 64, 0, stream>>>(pool1, fc1_w, fc1_b, rw1, 64);
    mix_kernel<64><<<128, 256, 0, stream>>>(w1, rw1, wmix1);
    nchw_to_nhwc_kernel<<<dim3(256, 16), 256, 0, stream>>>(x, xT);
    conv_mfma2_kernel<64, true><<<1024, 512, 0, stream>>>(
        xT, wmix1, scsh1, nullptr, hT, zp);

    // ---- layer 2 ----
    pool2a_kernel<<<dim3(16, 64), 256, 0, stream>>>(hT, part);
    pool2b_route2_kernel<<<16, 128, 0, stream>>>(part, fc2_w, fc2_b, rw2);
    mix_kernel<128><<<128, 256, 0, stream>>>(w2, rw2, wmix2);
    conv_mfma2_kernel<128, false><<<1024, 512, 0, stream>>>(
        hT, wmix2, scsh2, out, nullptr, zp);
}

// Round 4
// 413.583 us; speedup vs baseline: 1.0011x; 1.0011x over previous
//
#include <hip/hip_runtime.h>
#include <math.h>

#define BN_EPS 1e-5f

typedef short bf16x8 __attribute__((ext_vector_type(8)));
typedef float f32x4 __attribute__((ext_vector_type(4)));
typedef unsigned short ushort8v __attribute__((ext_vector_type(8)));
typedef unsigned int uint;
typedef unsigned short ushort;

__device__ inline ushort f2bf(float f) {           // RNE float->bf16
    uint u = __float_as_uint(f);
    uint r = u + 0x7FFFu + ((u >> 16) & 1u);
    return (ushort)(r >> 16);
}
__device__ inline float bf2f(ushort u) { return __uint_as_float(((uint)u) << 16); }

// ---------------------------------------------------------------------------
// Per-channel scale/shift for both BN layers: y = acc*sc + sh, then ReLU.
// ---------------------------------------------------------------------------
__global__ void scsh_kernel(const float* b1, const float* g1, const float* bb1,
                            const float* m1, const float* v1,
                            const float* b2, const float* g2, const float* bb2,
                            const float* m2, const float* v2,
                            float* scsh1, float* scsh2) {
    int t = threadIdx.x;
    if (t < 128) {
        float sc = g1[t] * rsqrtf(v1[t] + BN_EPS);
        scsh1[t] = sc;
        scsh1[128 + t] = (b1[t] - m1[t]) * sc + bb1[t];
    } else {
        int c = t - 128;
        float sc = g2[c] * rsqrtf(v2[c] + BN_EPS);
        scsh2[c] = sc;
        scsh2[128 + c] = (b2[c] - m2[c]) * sc + bb2[c];
    }
}

// ---------------------------------------------------------------------------
// x fp32 NCHW [16][64][128][128] -> xT bf16 chunk-planar [b][h][cc2][w][32ci]
// + fused adaptive-avg-pool partial sums (atomicAdd raw sums into pooled1).
// ---------------------------------------------------------------------------
__global__ void xprep_kernel(const float* __restrict__ x, ushort* __restrict__ xT,
                             float* __restrict__ pooled1) {
    __shared__ float t[64][65];
    const int b = blockIdx.y;
    const int p0 = blockIdx.x * 64;
    const int tid = threadIdx.x;
#pragma unroll
    for (int it = 0; it < 16; ++it) {
        const int idx = it * 256 + tid;
        const int ci = idx >> 6, p = idx & 63;
        t[ci][p] = x[((size_t)b * 64 + ci) * 16384 + p0 + p];
    }
    __syncthreads();
    const int h = p0 >> 7;
#pragma unroll
    for (int it = 0; it < 2; ++it) {
        const int p = it * 32 + (tid >> 3);
        const int w = (p0 & 127) + p;
        const int c0 = (tid & 7) * 8;
        const int cc = c0 >> 5, c32 = c0 & 31;
        ushort8v u;
#pragma unroll
        for (int j = 0; j < 8; ++j) u[j] = f2bf(t[c0 + j][p]);
        *(ushort8v*)&xT[((((size_t)b * 128 + h) * 2 + cc) * 128 + w) * 32 + c32] = u;
    }
    if (tid < 64) {
        float s = 0.f;
#pragma unroll 8
        for (int p = 0; p < 64; ++p) s += t[tid][p];
        atomicAdd(&pooled1[b * 64 + tid], s);
    }
}

// ---------------------------------------------------------------------------
// Pool hT (bf16 chunk-planar [b][h][cc4][w][32c]) -> pooled2 raw sums (atomic).
// grid (16, 32): each block sums 4 rows.
// ---------------------------------------------------------------------------
__global__ void pool2h_kernel(const ushort* __restrict__ hT, float* __restrict__ pooled2) {
    const int b = blockIdx.x, s4 = blockIdx.y;
    const int tid = threadIdx.x;
    const int cpair = tid & 15, cc = (tid >> 4) & 3, g = tid >> 6;
    float s0 = 0.f, s1 = 0.f;
    for (int r = 0; r < 4; ++r) {
        const size_t base = (((size_t)(b * 128 + s4 * 4 + r) * 4 + cc) * 4096) + cpair * 2;
#pragma unroll 8
        for (int w_ = 0; w_ < 32; ++w_) {
            const uint v = *(const uint*)&hT[base + (size_t)(g * 32 + w_) * 32];
            s0 += bf2f((ushort)(v & 0xffffu));
            s1 += bf2f((ushort)(v >> 16));
        }
    }
    __shared__ float sp[4][128];
    sp[g][cc * 32 + cpair * 2] = s0;
    sp[g][cc * 32 + cpair * 2 + 1] = s1;
    __syncthreads();
    if (tid < 128)
        atomicAdd(&pooled2[b * 128 + tid], sp[0][tid] + sp[1][tid] + sp[2][tid] + sp[3][tid]);
}

// ---------------------------------------------------------------------------
// Routing (from raw pooled sums) + expert mix, fused.
// wmix[b][tap][co][ci] (bf16) = sum_e rw[b,e] * w[e][co][ci][tap]
// ---------------------------------------------------------------------------
template <int C>
__global__ void mix_route_kernel(const float* __restrict__ w, const float* __restrict__ pooled,
                                 const float* __restrict__ fcw, const float* __restrict__ fcb,
                                 ushort* __restrict__ wmix) {
    __shared__ float rwl[48];
    const int tid = threadIdx.x;
    if (tid < 48) {
        const int bb = tid / 3, e = tid % 3;
        float d = 0.f;
        for (int c = 0; c < C; ++c) d += pooled[bb * C + c] * fcw[e * C + c];
        const float s = fcb[e] + d * (1.f / 16384.f);
        rwl[tid] = 1.f / (1.f + expf(-s));
    }
    __syncthreads();
    const int co = blockIdx.x;
    for (int b = 0; b < 16; ++b) {
        const float r0 = rwl[b * 3 + 0], r1 = rwl[b * 3 + 1], r2 = rwl[b * 3 + 2];
        for (int idx = tid; idx < C * 9; idx += 256) {
            const int ci = idx & (C - 1);
            const int tap = idx / C;
            const size_t o = ((size_t)co * C + ci) * 9 + tap;
            const float m = r0 * w[o]
                          + r1 * w[o + (size_t)128 * C * 9]
                          + r2 * w[o + (size_t)2 * 128 * C * 9];
            wmix[(((size_t)b * 9 + tap) * 128 + co) * C + ci] = f2bf(m);
        }
    }
}

// ---------------------------------------------------------------------------
// MFMA implicit-GEMM conv3x3(pad1) + fused bias/BN/ReLU. v4:
//  - input chunk-planar [b][h][cc][w][32ci]: staging = contiguous 8KB per row
//  - LDS tile [4 rows][130 cols][32 ci] (halo cols pre-zeroed once), dbuf
//  - ci-octet XOR swizzle (g ^ (col&3)) applied on pre-swizzled global source
//  - stage issued AFTER all af loads of the chunk (no vmcnt ordering poison)
//  - LDS-transpose epilogue -> perfectly contiguous global stores
// ---------------------------------------------------------------------------
template <int CIN, bool TO_BF16>
__global__ __launch_bounds__(512, 4)
void conv_mfma3_kernel(const ushort* __restrict__ xT, const ushort* __restrict__ wmix,
                       const float* __restrict__ scsh,
                       float* __restrict__ outf, ushort* __restrict__ outh,
                       const ushort* __restrict__ zp) {
    constexpr int NCC = CIN / 32;
    __shared__ __align__(16) char smem[66560];   // 2 x 33,280B input dbuf / 64KB epilogue

    const int g0 = blockIdx.x;
    const int wsw = ((g0 & 7) << 7) | (g0 >> 3);  // 1024 wgs: 128 consecutive per XCD
    const int b = wsw >> 6;
    const int rt = wsw & 63;                      // output rows rt*2, rt*2+1

    const int tid = threadIdx.x;
    const int lane = tid & 63, wid = tid >> 6;
    const int wm = wid >> 2, wn = wid & 3;
    const int l15 = lane & 15, lg = lane >> 4;

    f32x4 acc[4][4];
#pragma unroll
    for (int i = 0; i < 4; ++i)
#pragma unroll
        for (int j = 0; j < 4; ++j) acc[i][j] = {0.f, 0.f, 0.f, 0.f};

    const ushort* inb = xT + (size_t)b * 128 * NCC * 4096;
    const ushort* wb = wmix + (size_t)b * 9 * 128 * CIN;

    int prow[4], pcol[4];
#pragma unroll
    for (int nf = 0; nf < 4; ++nf) {
        const int px = wn * 64 + nf * 16 + l15;
        prow[nf] = px >> 7;
        pcol[nf] = px & 127;
    }

    // ---- stage chunk cc into buffer bufi: 32 x 1KB gllds, contiguous rows ----
    auto stage = [&](int bufi, int cc) {
#pragma unroll
        for (int u = 0; u < 4; ++u) {
            const int j = wid + u * 8;        // 0..31
            const int r = j >> 3;             // tile row 0..3
            const int jj = j & 7;
            const int q = jj * 64 + lane;     // 0..511
            const int colm1 = q >> 2;         // w 0..127
            const int g = q & 3;
            const int gs = g ^ ((colm1 + 1) & 3);
            const int hg = rt * 2 - 1 + r;
            const ushort* src;
            if ((unsigned)hg < 128u)
                src = inb + ((((size_t)hg * NCC + cc) * 128 + colm1) * 32) + gs * 8;
            else
                src = zp + (lane & 3) * 8;
            const int dstByte = bufi * 33280 + (r * 520 + 4 + q) * 16;
            __builtin_amdgcn_global_load_lds(
                (const __attribute__((address_space(1))) void*)src,
                (__attribute__((address_space(3))) void*)(smem + dstByte), 16, 0, 0);
        }
    };

    auto taps = [&](int bufi, int cc) {
        const int ci0 = cc * 32;
        const int bbase = bufi * 33280;
#pragma unroll
        for (int tap = 0; tap < 9; ++tap) {
            const int dy = tap / 3, dx = tap - dy * 3;
            bf16x8 af[4];
#pragma unroll
            for (int mf = 0; mf < 4; ++mf) {
                const int co = wm * 64 + mf * 16 + l15;
                af[mf] = *(const bf16x8*)&wb[(size_t)(tap * 128 + co) * CIN + ci0 + lg * 8];
            }
#pragma unroll
            for (int nf = 0; nf < 4; ++nf) {
                const int col = pcol[nf] + dx;
                const int gran = (prow[nf] + dy) * 520 + col * 4 + (lg ^ (col & 3));
                const bf16x8 bv = *(const bf16x8*)&smem[bbase + gran * 16];
#pragma unroll
                for (int mf = 0; mf < 4; ++mf)
                    acc[mf][nf] = __builtin_amdgcn_mfma_f32_16x16x32_bf16(
                        af[mf], bv, acc[mf][nf], 0, 0, 0);
            }
        }
    };

    // zero the halo columns (cols 0 and 129, both buffers) once
    if (tid < 64) {
        const int bi = tid >> 5, rr = (tid >> 3) & 3, e = tid & 7;
        const int gr = rr * 520 + (e < 4 ? e : 512 + e);
        *(f32x4*)&smem[bi * 33280 + gr * 16] = f32x4{0.f, 0.f, 0.f, 0.f};
    }
    stage(0, 0);
    asm volatile("s_waitcnt vmcnt(0)" ::: "memory");
    __syncthreads();

    for (int cc = 0; cc < NCC; ++cc) {
        const int cur = cc & 1;
        taps(cur, cc);
        if (cc + 1 < NCC) {
            stage(cur ^ 1, cc + 1);
            asm volatile("s_waitcnt vmcnt(0)" ::: "memory");
            __syncthreads();
        }
    }
    __syncthreads();   // all taps reads done before LDS reuse

    if constexpr (TO_BF16) {
        // ---- epilogue 1: bf16 chunk-planar hT via LDS transpose ----
#pragma unroll
        for (int mf = 0; mf < 4; ++mf) {
            const int co0 = wm * 64 + mf * 16 + lg * 4;
            const f32x4 sc = *(const f32x4*)&scsh[co0];
            const f32x4 sh = *(const f32x4*)&scsh[128 + co0];
            const int cc_ = wm * 2 + (mf >> 1);
            const int k = (mf & 1) * 2 + (lg >> 1);
#pragma unroll
            for (int nf = 0; nf < 4; ++nf) {
                const int row = prow[nf], w = pcol[nf];
                float v[4];
#pragma unroll
                for (int r = 0; r < 4; ++r) {
                    float y = fmaf(acc[mf][nf][r], sc[r], sh[r]);
                    v[r] = y > 0.f ? y : 0.f;
                }
                uint2 pk;
                pk.x = (uint)f2bf(v[0]) | ((uint)f2bf(v[1]) << 16);
                pk.y = (uint)f2bf(v[2]) | ((uint)f2bf(v[3]) << 16);
                const int G16 = ((row * 4 + cc_) * 128 + w) * 4 + (k ^ (w & 3));
                *(uint2*)&smem[G16 * 16 + (lg & 1) * 8] = pk;
            }
        }
        __syncthreads();
        const size_t obase = (size_t)b * 2097152 + (size_t)rt * 32768;  // ushort elems
#pragma unroll
        for (int rr = 0; rr < 8; ++rr) {
            const int G = rr * 512 + tid;
            const int w = (G >> 2) & 127, k = G & 3;
            const uint4 v = *(const uint4*)&smem[((G & ~3) + (k ^ (w & 3))) * 16];
            *(uint4*)&outh[obase + (size_t)G * 8] = v;
        }
    } else {
        // ---- epilogue 2: fp32 NCHW out via LDS transpose, two 64-co passes ----
#pragma unroll
        for (int p = 0; p < 2; ++p) {
            if (wm == p) {
#pragma unroll
                for (int mf = 0; mf < 4; ++mf) {
                    const int co0 = wm * 64 + mf * 16 + lg * 4;
                    const f32x4 sc = *(const f32x4*)&scsh[co0];
                    const f32x4 sh = *(const f32x4*)&scsh[128 + co0];
#pragma unroll
                    for (int nf = 0; nf < 4; ++nf) {
                        const int row = prow[nf], w = pcol[nf];
#pragma unroll
                        for (int r = 0; r < 4; ++r) {
                            float y = fmaf(acc[mf][nf][r], sc[r], sh[r]);
                            y = y > 0.f ? y : 0.f;
                            const int co_l = mf * 16 + lg * 4 + r;
                            *(float*)&smem[(co_l * 256 + row * 128 + w) * 4] = y;
                        }
                    }
                }
            }
            __syncthreads();
            const size_t obase2 = ((size_t)b * 128 + p * 64) * 16384 + (size_t)rt * 256;
#pragma unroll
            for (int rr = 0; rr < 8; ++rr) {
                const int G = rr * 512 + tid;
                const int co_l = G >> 6, rem = G & 63, row = rem >> 5, w4 = rem & 31;
                const uint4 v = *(const uint4*)&smem[G * 16];
                *(uint4*)&outf[obase2 + (size_t)co_l * 16384 + row * 128 + w4 * 4] = v;
            }
            if (p == 0) __syncthreads();
        }
    }
}

// ---------------------------------------------------------------------------
extern "C" void kernel_launch(void* const* d_in, const int* in_sizes, int n_in,
                              void* d_out, int out_size, void* d_ws, size_t ws_size,
                              hipStream_t stream) {
    const float* x     = (const float*)d_in[0];
    const float* w1    = (const float*)d_in[1];
    const float* b1    = (const float*)d_in[2];
    const float* fc1_w = (const float*)d_in[3];
    const float* fc1_b = (const float*)d_in[4];
    const float* bn1g  = (const float*)d_in[5];
    const float* bn1b  = (const float*)d_in[6];
    const float* bn1m  = (const float*)d_in[7];
    const float* bn1v  = (const float*)d_in[8];
    const float* w2    = (const float*)d_in[9];
    const float* b2    = (const float*)d_in[10];
    const float* fc2_w = (const float*)d_in[11];
    const float* fc2_b = (const float*)d_in[12];
    const float* bn2g  = (const float*)d_in[13];
    const float* bn2b  = (const float*)d_in[14];
    const float* bn2m  = (const float*)d_in[15];
    const float* bn2v  = (const float*)d_in[16];

    float* out = (float*)d_out;
    char* ws = (char*)d_ws;

    // workspace layout (bytes)
    ushort* hT    = (ushort*)(ws + 0);            //  67,108,864
    ushort* xT    = (ushort*)(ws + 67108864);     //  33,554,432
    ushort* wmix1 = (ushort*)(ws + 100663296);    //   2,359,296
    ushort* wmix2 = (ushort*)(ws + 103022592);    //   4,718,592
    float*  pool1 = (float*) (ws + 107741184);    //       4,096
    float*  pool2 = (float*) (ws + 107745280);    //       8,192
    float*  scsh1 = (float*) (ws + 107753472);    //       1,024
    float*  scsh2 = (float*) (ws + 107754496);    //       1,024
    ushort* zp    = (ushort*)(ws + 107755520);    //          64 (zero page)

    hipMemsetAsync(zp, 0, 64, stream);
    hipMemsetAsync(pool1, 0, 4096, stream);
    hipMemsetAsync(pool2, 0, 8192, stream);

    scsh_kernel<<<1, 256, 0, stream>>>(b1, bn1g, bn1b, bn1m, bn1v,
                                       b2, bn2g, bn2b, bn2m, bn2v, scsh1, scsh2);

    // ---- layer 1 ----
    xprep_kernel<<<dim3(256, 16), 256, 0, stream>>>(x, xT, pool1);
    mix_route_kernel<64><<<128, 256, 0, stream>>>(w1, pool1, fc1_w, fc1_b, wmix1);
    conv_mfma3_kernel<64, true><<<1024, 512, 0, stream>>>(
        xT, wmix1, scsh1, nullptr, hT, zp);

    // ---- layer 2 ----
    pool2h_kernel<<<dim3(16, 32), 256, 0, stream>>>(hT, pool2);
    mix_route_kernel<128><<<128, 256, 0, stream>>>(w2, pool2, fc2_w, fc2_b, wmix2);
    conv_mfma3_kernel<128, false><<<1024, 512, 0, stream>>>(
        hT, wmix2, scsh2, out, nullptr, zp);
}

// Round 5
// 269.943 us; speedup vs baseline: 1.5338x; 1.5321x over previous
//
#include <hip/hip_runtime.h>
#include <math.h>

#define BN_EPS 1e-5f

typedef short bf16x8 __attribute__((ext_vector_type(8)));
typedef float f32x4 __attribute__((ext_vector_type(4)));
typedef unsigned short ushort8v __attribute__((ext_vector_type(8)));
typedef unsigned int uint;
typedef unsigned short ushort;

__device__ inline ushort f2bf(float f) {           // RNE float->bf16
    uint u = __float_as_uint(f);
    uint r = u + 0x7FFFu + ((u >> 16) & 1u);
    return (ushort)(r >> 16);
}
__device__ inline float bf2f(ushort u) { return __uint_as_float(((uint)u) << 16); }

// ---------------------------------------------------------------------------
// Per-channel scale/shift for both BN layers: y = acc*sc + sh, then ReLU.
// ---------------------------------------------------------------------------
__global__ void scsh_kernel(const float* b1, const float* g1, const float* bb1,
                            const float* m1, const float* v1,
                            const float* b2, const float* g2, const float* bb2,
                            const float* m2, const float* v2,
                            float* scsh1, float* scsh2) {
    int t = threadIdx.x;
    if (t < 128) {
        float sc = g1[t] * rsqrtf(v1[t] + BN_EPS);
        scsh1[t] = sc;
        scsh1[128 + t] = (b1[t] - m1[t]) * sc + bb1[t];
    } else {
        int c = t - 128;
        float sc = g2[c] * rsqrtf(v2[c] + BN_EPS);
        scsh2[c] = sc;
        scsh2[128 + c] = (b2[c] - m2[c]) * sc + bb2[c];
    }
}

// ---------------------------------------------------------------------------
// x fp32 NCHW [16][64][128][128] -> xT bf16 chunk-planar [b][h][cc2][w][32ci]
// + fused adaptive-avg-pool partial sums (atomicAdd raw sums into pooled1).
// ---------------------------------------------------------------------------
__global__ void xprep_kernel(const float* __restrict__ x, ushort* __restrict__ xT,
                             float* __restrict__ pooled1) {
    __shared__ float t[64][65];
    const int b = blockIdx.y;
    const int p0 = blockIdx.x * 64;
    const int tid = threadIdx.x;
#pragma unroll
    for (int it = 0; it < 16; ++it) {
        const int idx = it * 256 + tid;
        const int ci = idx >> 6, p = idx & 63;
        t[ci][p] = x[((size_t)b * 64 + ci) * 16384 + p0 + p];
    }
    __syncthreads();
    const int h = p0 >> 7;
#pragma unroll
    for (int it = 0; it < 2; ++it) {
        const int p = it * 32 + (tid >> 3);
        const int w = (p0 & 127) + p;
        const int c0 = (tid & 7) * 8;
        const int cc = c0 >> 5, c32 = c0 & 31;
        ushort8v u;
#pragma unroll
        for (int j = 0; j < 8; ++j) u[j] = f2bf(t[c0 + j][p]);
        *(ushort8v*)&xT[((((size_t)b * 128 + h) * 2 + cc) * 128 + w) * 32 + c32] = u;
    }
    if (tid < 64) {
        float s = 0.f;
#pragma unroll 8
        for (int p = 0; p < 64; ++p) s += t[tid][p];
        atomicAdd(&pooled1[b * 64 + tid], s);
    }
}

// ---------------------------------------------------------------------------
// Pool hT (bf16 chunk-planar [b][h][cc4][w][32c]) -> pooled2 raw sums (atomic).
// ---------------------------------------------------------------------------
__global__ void pool2h_kernel(const ushort* __restrict__ hT, float* __restrict__ pooled2) {
    const int b = blockIdx.x, s4 = blockIdx.y;
    const int tid = threadIdx.x;
    const int cpair = tid & 15, cc = (tid >> 4) & 3, g = tid >> 6;
    float s0 = 0.f, s1 = 0.f;
    for (int r = 0; r < 4; ++r) {
        const size_t base = (((size_t)(b * 128 + s4 * 4 + r) * 4 + cc) * 4096) + cpair * 2;
#pragma unroll 8
        for (int w_ = 0; w_ < 32; ++w_) {
            const uint v = *(const uint*)&hT[base + (size_t)(g * 32 + w_) * 32];
            s0 += bf2f((ushort)(v & 0xffffu));
            s1 += bf2f((ushort)(v >> 16));
        }
    }
    __shared__ float sp[4][128];
    sp[g][cc * 32 + cpair * 2] = s0;
    sp[g][cc * 32 + cpair * 2 + 1] = s1;
    __syncthreads();
    if (tid < 128)
        atomicAdd(&pooled2[b * 128 + tid], sp[0][tid] + sp[1][tid] + sp[2][tid] + sp[3][tid]);
}

// ---------------------------------------------------------------------------
// Routing + expert mix, writing wmix in the conv kernel's LDS image:
//   per (b, cc, cog): contiguous 36,864B block, granule layout
//   (tap*64 + co64)*4 + (lg ^ ((co64>>1)&3)), each granule = 8 bf16 of ci.
// ---------------------------------------------------------------------------
template <int CIN>
__global__ void mix_route_kernel(const float* __restrict__ w, const float* __restrict__ pooled,
                                 const float* __restrict__ fcw, const float* __restrict__ fcb,
                                 ushort* __restrict__ wmix) {
    constexpr int NCC = CIN / 32;
    __shared__ float rwl[48];
    const int tid = threadIdx.x;
    if (tid < 48) {
        const int bb = tid / 3, e = tid % 3;
        float d = 0.f;
        for (int c = 0; c < CIN; ++c) d += pooled[bb * CIN + c] * fcw[e * CIN + c];
        const float s = fcb[e] + d * (1.f / 16384.f);
        rwl[tid] = 1.f / (1.f + expf(-s));
    }
    __syncthreads();
    const int co = blockIdx.x;           // 0..127 global co
    const int cog = co >> 6, co64 = co & 63;
    const int sw = (co64 >> 1) & 3;
    for (int b = 0; b < 16; ++b) {
        const float r0 = rwl[b * 3 + 0], r1 = rwl[b * 3 + 1], r2 = rwl[b * 3 + 2];
        for (int idx = tid; idx < CIN * 9; idx += 256) {
            const int ci = idx & (CIN - 1);
            const int tap = idx / CIN;
            const size_t o = ((size_t)co * CIN + ci) * 9 + tap;
            const float m = r0 * w[o]
                          + r1 * w[o + (size_t)128 * CIN * 9]
                          + r2 * w[o + (size_t)2 * 128 * CIN * 9];
            const int cc = ci >> 5, lg = (ci >> 3) & 3, e = ci & 7;
            const size_t dst = (((size_t)(b * NCC + cc) * 2) + cog) * 18432
                             + ((size_t)(tap * 64 + co64) * 4 + (lg ^ sw)) * 8 + e;
            wmix[dst] = f2bf(m);
        }
    }
}

// ---------------------------------------------------------------------------
// MFMA implicit-GEMM conv3x3(pad1) + fused bias/BN/ReLU. v5:
//  - tile M=64co x N=256px (2 rows), 8 waves (2 co-halves x 4 px-quarters)
//  - BOTH operands staged to LDS via global_load_lds (dbuf); tap loop is pure
//    ds_read+MFMA -> NO vmem waits inside compute; the only stage drain is the
//    compiler's vmcnt(0) before the per-chunk barrier, hidden under 576 MFMAs
//  - period-8 XOR swizzle (lg ^ ((c>>1)&3)) on both operands: conflict-free
//  - LDS-transpose epilogues: perfectly contiguous global stores
// ---------------------------------------------------------------------------
template <int CIN, bool TO_BF16>
__global__ __launch_bounds__(512, 2)
void conv_mfma4_kernel(const ushort* __restrict__ xT, const ushort* __restrict__ wmix,
                       const float* __restrict__ scsh,
                       float* __restrict__ outf, ushort* __restrict__ outh,
                       const ushort* __restrict__ zp) {
    constexpr int NCC = CIN / 32;
    // [0,66560): input dbuf 2x33280 | [66560,140288): weight dbuf 2x36864
    __shared__ __align__(16) char smem[140288];

    const int L = ((blockIdx.x & 7) << 8) | (blockIdx.x >> 3);  // 256/XCD = 2 images
    const int cog = L & 1;
    const int rt = (L >> 1) & 63;      // output rows rt*2, rt*2+1
    const int b = L >> 7;

    const int tid = threadIdx.x;
    const int lane = tid & 63, wid = tid >> 6;
    const int wm = wid >> 2, wn = wid & 3;
    const int l15 = lane & 15, lg = lane >> 4;

    f32x4 acc[2][4];
#pragma unroll
    for (int i = 0; i < 2; ++i)
#pragma unroll
        for (int j = 0; j < 4; ++j) acc[i][j] = {0.f, 0.f, 0.f, 0.f};

    const ushort* inb = xT + (size_t)b * 128 * NCC * 4096;

    int prow[4], pcol[4];
#pragma unroll
    for (int nf = 0; nf < 4; ++nf) {
        const int px = wn * 64 + nf * 16 + l15;
        prow[nf] = px >> 7;
        pcol[nf] = px & 127;
    }

    // ---- stage chunk cc into dbuf bufi: 32 input + 36 weight 1KB gllds ----
    auto stage = [&](int bufi, int cc) {
        const ushort* wsrc = wmix + (((size_t)(b * NCC + cc) * 2) + cog) * 18432;
        for (int j = wid; j < 68; j += 8) {
            if (j < 32) {
                const int r = j >> 3;
                const int q = (j & 7) * 64 + lane;
                const int colm1 = q >> 2;         // w 0..127
                const int g = q & 3;
                const int gs = g ^ (((colm1 + 1) >> 1) & 3);
                const int hg = rt * 2 - 1 + r;
                const ushort* src = ((unsigned)hg < 128u)
                    ? inb + (((size_t)(hg * NCC + cc) * 128 + colm1) * 32) + gs * 8
                    : zp + (lane & 3) * 8;
                __builtin_amdgcn_global_load_lds(
                    (const __attribute__((address_space(1))) void*)src,
                    (__attribute__((address_space(3))) void*)(smem + bufi * 33280 + (r * 520 + 4 + q) * 16),
                    16, 0, 0);
            } else {
                const int k = j - 32;             // 0..35
                const ushort* src = wsrc + k * 512 + lane * 8;
                __builtin_amdgcn_global_load_lds(
                    (const __attribute__((address_space(1))) void*)src,
                    (__attribute__((address_space(3))) void*)(smem + 66560 + bufi * 36864 + k * 1024 + lane * 16),
                    16, 0, 0);
            }
        }
    };

    // ---- compute all 9 taps of a chunk: pure ds_read + MFMA ----
    auto taps = [&](int bufi) {
        const char* ldsI = smem + bufi * 33280;
        const char* ldsW = smem + 66560 + bufi * 36864;
#pragma unroll
        for (int tap = 0; tap < 9; ++tap) {
            const int dy = tap / 3, dx = tap - dy * 3;
            bf16x8 af[2];
#pragma unroll
            for (int mf = 0; mf < 2; ++mf) {
                const int co = wm * 32 + mf * 16 + l15;
                const int gA = (tap * 64 + co) * 4 + (lg ^ ((co >> 1) & 3));
                af[mf] = *(const bf16x8*)(ldsW + gA * 16);
            }
#pragma unroll
            for (int nf = 0; nf < 4; ++nf) {
                const int col = pcol[nf] + dx;
                const int gB = (prow[nf] + dy) * 520 + col * 4 + (lg ^ ((col >> 1) & 3));
                const bf16x8 bv = *(const bf16x8*)(ldsI + gB * 16);
#pragma unroll
                for (int mf = 0; mf < 2; ++mf)
                    acc[mf][nf] = __builtin_amdgcn_mfma_f32_16x16x32_bf16(
                        af[mf], bv, acc[mf][nf], 0, 0, 0);
            }
        }
    };

    // zero the halo columns (cols 0 and 129, both input buffers) once
    if (tid < 64) {
        const int bi = tid >> 5, rr = (tid >> 3) & 3, e = tid & 7;
        const int gr = rr * 520 + (e < 4 ? e : 512 + e);
        *(f32x4*)&smem[bi * 33280 + gr * 16] = f32x4{0.f, 0.f, 0.f, 0.f};
    }
    stage(0, 0);
    __syncthreads();   // compiler emits vmcnt(0) before barrier -> buf0 ready

#pragma unroll
    for (int cc = 0; cc < NCC; ++cc) {
        if (cc + 1 < NCC) stage((cc & 1) ^ 1, cc + 1);   // async, no wait
        __builtin_amdgcn_sched_barrier(0);               // keep issue order
        taps(cc & 1);                                    // no vmem waits inside
        __syncthreads();                                 // drain = hidden under taps
    }

    // ---- epilogues: y = relu(acc*sc + sh), LDS transpose, contiguous stores ----
    if constexpr (TO_BF16) {
        float* sf = (float*)smem;                        // [256 px][68]
#pragma unroll
        for (int mf = 0; mf < 2; ++mf) {
            const int co_l = wm * 32 + mf * 16 + lg * 4;
            const f32x4 sc = *(const f32x4*)&scsh[cog * 64 + co_l];
            const f32x4 sh = *(const f32x4*)&scsh[128 + cog * 64 + co_l];
#pragma unroll
            for (int nf = 0; nf < 4; ++nf) {
                const int px = wn * 64 + nf * 16 + l15;
                f32x4 v;
#pragma unroll
                for (int r = 0; r < 4; ++r) {
                    float y = fmaf(acc[mf][nf][r], sc[r], sh[r]);
                    v[r] = y > 0.f ? y : 0.f;
                }
                *(f32x4*)&sf[px * 68 + co_l] = v;
            }
        }
        __syncthreads();
        const int rc = tid >> 7, r = rc >> 1, cl = rc & 1, w = tid & 127;
        const float* src = &sf[(r * 128 + w) * 68 + cl * 32];
        const size_t hbase = (((size_t)(b * 128 + rt * 2 + r) * 4) + cog * 2 + cl) * 4096
                           + (size_t)w * 32;
#pragma unroll
        for (int k = 0; k < 4; ++k) {
            ushort8v u;
#pragma unroll
            for (int j = 0; j < 8; ++j) u[j] = f2bf(src[k * 8 + j]);
            *(ushort8v*)&outh[hbase + k * 8] = u;
        }
    } else {
        float* sf = (float*)smem;                        // [64 co][260]
#pragma unroll
        for (int mf = 0; mf < 2; ++mf) {
            const int co_l = wm * 32 + mf * 16 + lg * 4;
            const f32x4 sc = *(const f32x4*)&scsh[cog * 64 + co_l];
            const f32x4 sh = *(const f32x4*)&scsh[128 + cog * 64 + co_l];
#pragma unroll
            for (int nf = 0; nf < 4; ++nf) {
                const int px = wn * 64 + nf * 16 + l15;
#pragma unroll
                for (int r = 0; r < 4; ++r) {
                    float y = fmaf(acc[mf][nf][r], sc[r], sh[r]);
                    sf[(co_l + r) * 260 + px] = y > 0.f ? y : 0.f;
                }
            }
        }
        __syncthreads();
        const int co = tid >> 3, p0 = (tid & 7) * 32;
        const int r = p0 >> 7, w0 = p0 & 127;
        float* dst = &outf[((size_t)(b * 128) + cog * 64 + co) * 16384
                           + (size_t)(rt * 2 + r) * 128 + w0];
        const float* src = &sf[co * 260 + p0];
#pragma unroll
        for (int k = 0; k < 8; ++k)
            *(f32x4*)&dst[k * 4] = *(const f32x4*)&src[k * 4];
    }
}

// ---------------------------------------------------------------------------
extern "C" void kernel_launch(void* const* d_in, const int* in_sizes, int n_in,
                              void* d_out, int out_size, void* d_ws, size_t ws_size,
                              hipStream_t stream) {
    const float* x     = (const float*)d_in[0];
    const float* w1    = (const float*)d_in[1];
    const float* b1    = (const float*)d_in[2];
    const float* fc1_w = (const float*)d_in[3];
    const float* fc1_b = (const float*)d_in[4];
    const float* bn1g  = (const float*)d_in[5];
    const float* bn1b  = (const float*)d_in[6];
    const float* bn1m  = (const float*)d_in[7];
    const float* bn1v  = (const float*)d_in[8];
    const float* w2    = (const float*)d_in[9];
    const float* b2    = (const float*)d_in[10];
    const float* fc2_w = (const float*)d_in[11];
    const float* fc2_b = (const float*)d_in[12];
    const float* bn2g  = (const float*)d_in[13];
    const float* bn2b  = (const float*)d_in[14];
    const float* bn2m  = (const float*)d_in[15];
    const float* bn2v  = (const float*)d_in[16];

    float* out = (float*)d_out;
    char* ws = (char*)d_ws;

    // workspace layout (bytes)
    ushort* hT    = (ushort*)(ws + 0);            //  67,108,864
    ushort* xT    = (ushort*)(ws + 67108864);     //  33,554,432
    ushort* wmix1 = (ushort*)(ws + 100663296);    //   2,359,296
    ushort* wmix2 = (ushort*)(ws + 103022592);    //   4,718,592
    float*  pool1 = (float*) (ws + 107741184);    //       4,096
    float*  pool2 = (float*) (ws + 107745280);    //       8,192
    float*  scsh1 = (float*) (ws + 107753472);    //       1,024
    float*  scsh2 = (float*) (ws + 107754496);    //       1,024
    ushort* zp    = (ushort*)(ws + 107755520);    //          64 (zero page)

    hipMemsetAsync(zp, 0, 64, stream);
    hipMemsetAsync(pool1, 0, 4096, stream);
    hipMemsetAsync(pool2, 0, 8192, stream);

    scsh_kernel<<<1, 256, 0, stream>>>(b1, bn1g, bn1b, bn1m, bn1v,
                                       b2, bn2g, bn2b, bn2m, bn2v, scsh1, scsh2);

    // ---- layer 1 ----
    xprep_kernel<<<dim3(256, 16), 256, 0, stream>>>(x, xT, pool1);
    mix_route_kernel<64><<<128, 256, 0, stream>>>(w1, pool1, fc1_w, fc1_b, wmix1);
    conv_mfma4_kernel<64, true><<<2048, 512, 0, stream>>>(
        xT, wmix1, scsh1, nullptr, hT, zp);

    // ---- layer 2 ----
    pool2h_kernel<<<dim3(16, 32), 256, 0, stream>>>(hT, pool2);
    mix_route_kernel<128><<<128, 256, 0, stream>>>(w2, pool2, fc2_w, fc2_b, wmix2);
    conv_mfma4_kernel<128, false><<<2048, 512, 0, stream>>>(
        hT, wmix2, scsh2, out, nullptr, zp);
}

// Round 6
// 213.364 us; speedup vs baseline: 1.9405x; 1.2652x over previous
//
#include <hip/hip_runtime.h>
#include <math.h>

#define BN_EPS 1e-5f

typedef short bf16x8 __attribute__((ext_vector_type(8)));
typedef float f32x4 __attribute__((ext_vector_type(4)));
typedef float f32x16 __attribute__((ext_vector_type(16)));
typedef unsigned short ushort8v __attribute__((ext_vector_type(8)));
typedef unsigned int uint;
typedef unsigned short ushort;

__device__ inline ushort f2bf(float f) {           // RNE float->bf16
    uint u = __float_as_uint(f);
    uint r = u + 0x7FFFu + ((u >> 16) & 1u);
    return (ushort)(r >> 16);
}
__device__ inline float bf2f(ushort u) { return __uint_as_float(((uint)u) << 16); }

// ---------------------------------------------------------------------------
// Per-channel scale/shift for both BN layers: y = acc*sc + sh, then ReLU.
// ---------------------------------------------------------------------------
__global__ void scsh_kernel(const float* b1, const float* g1, const float* bb1,
                            const float* m1, const float* v1,
                            const float* b2, const float* g2, const float* bb2,
                            const float* m2, const float* v2,
                            float* scsh1, float* scsh2) {
    int t = threadIdx.x;
    if (t < 128) {
        float sc = g1[t] * rsqrtf(v1[t] + BN_EPS);
        scsh1[t] = sc;
        scsh1[128 + t] = (b1[t] - m1[t]) * sc + bb1[t];
    } else {
        int c = t - 128;
        float sc = g2[c] * rsqrtf(v2[c] + BN_EPS);
        scsh2[c] = sc;
        scsh2[128 + c] = (b2[c] - m2[c]) * sc + bb2[c];
    }
}

// ---------------------------------------------------------------------------
// x fp32 NCHW [16][64][128][128] -> xT bf16 16ci-planar [b][h][cc4][w][16]
// + fused pool partial sums (atomicAdd raw sums into pooled1).
// ---------------------------------------------------------------------------
__global__ void xprep_kernel(const float* __restrict__ x, ushort* __restrict__ xT,
                             float* __restrict__ pooled1) {
    __shared__ float t[64][65];
    const int b = blockIdx.y;
    const int p0 = blockIdx.x * 64;
    const int tid = threadIdx.x;
#pragma unroll
    for (int it = 0; it < 16; ++it) {
        const int idx = it * 256 + tid;
        const int ci = idx >> 6, p = idx & 63;
        t[ci][p] = x[((size_t)b * 64 + ci) * 16384 + p0 + p];
    }
    __syncthreads();
    const int h = p0 >> 7;
#pragma unroll
    for (int it = 0; it < 2; ++it) {
        const int p = it * 32 + (tid >> 3);
        const int w = (p0 & 127) + p;
        const int c0 = (tid & 7) * 8;
        const int cc = c0 >> 4;
        ushort8v u;
#pragma unroll
        for (int j = 0; j < 8; ++j) u[j] = f2bf(t[c0 + j][p]);
        *(ushort8v*)&xT[(((size_t)(b * 128 + h) * 4 + cc) * 128 + w) * 16 + (c0 & 15)] = u;
    }
    if (tid < 64) {
        float s = 0.f;
#pragma unroll 8
        for (int p = 0; p < 64; ++p) s += t[tid][p];
        atomicAdd(&pooled1[b * 64 + tid], s);
    }
}

// ---------------------------------------------------------------------------
// Pool hT (bf16 16ci-planar [b][h][cc8][w][16]) -> pooled2 raw sums (atomic).
// grid (16, 32): each block sums 4 rows, fully coalesced 16B/lane reads.
// ---------------------------------------------------------------------------
__global__ void pool2h_kernel(const ushort* __restrict__ hT, float* __restrict__ pooled2) {
    const int b = blockIdx.x, slab = blockIdx.y;
    const int tid = threadIdx.x;                  // 256
    const int cc = tid >> 5, o = (tid >> 4) & 1, wb = tid & 15;
    float a[8] = {0.f, 0.f, 0.f, 0.f, 0.f, 0.f, 0.f, 0.f};
    for (int r = 0; r < 4; ++r) {
        const int h = slab * 4 + r;
        const ushort* base = hT + ((size_t)(b * 128 + h) * 8 + cc) * 2048 + o * 8;
#pragma unroll
        for (int k = 0; k < 8; ++k) {
            const ushort8v u = *(const ushort8v*)(base + (wb + k * 16) * 16);
#pragma unroll
            for (int j = 0; j < 8; ++j) a[j] += bf2f(u[j]);
        }
    }
    __shared__ float sp[16][8][17];
    const int grp0 = cc * 2 + o;
#pragma unroll
    for (int j = 0; j < 8; ++j) sp[grp0][j][wb] = a[j];
    __syncthreads();
    if (tid < 128) {
        const int grp = tid >> 3, j = tid & 7;
        float s = 0.f;
#pragma unroll
        for (int k = 0; k < 16; ++k) s += sp[grp][j][k];
        const int c = (grp >> 1) * 16 + (grp & 1) * 8 + j;
        atomicAdd(&pooled2[b * 128 + c], s);
    }
}

// ---------------------------------------------------------------------------
// Routing (from raw pooled sums) + expert mix, writing wmix as the conv
// kernel's LDS weight image: per (b,cc16): 2304 granules of 16B,
// granule = (tap*128+co)*2 + (oct ^ ((co>>2)&1)), elems = 8 ci.
// ---------------------------------------------------------------------------
template <int CIN>
__global__ void mix_route_kernel(const float* __restrict__ w, const float* __restrict__ pooled,
                                 const float* __restrict__ fcw, const float* __restrict__ fcb,
                                 ushort* __restrict__ wmix) {
    constexpr int NCC = CIN / 16;
    __shared__ float rwl[48];
    const int tid = threadIdx.x;
    if (tid < 48) {
        const int bb = tid / 3, e = tid % 3;
        float d = 0.f;
        for (int c = 0; c < CIN; ++c) d += pooled[bb * CIN + c] * fcw[e * CIN + c];
        const float s = fcb[e] + d * (1.f / 16384.f);
        rwl[tid] = 1.f / (1.f + expf(-s));
    }
    __syncthreads();
    const int co = blockIdx.x;           // 0..127
    const int sw = (co >> 2) & 1;
    for (int b = 0; b < 16; ++b) {
        const float r0 = rwl[b * 3 + 0], r1 = rwl[b * 3 + 1], r2 = rwl[b * 3 + 2];
        for (int idx = tid; idx < CIN * 9; idx += 256) {
            const int ci = idx & (CIN - 1);
            const int tap = idx / CIN;
            const size_t off = ((size_t)co * CIN + ci) * 9 + tap;
            const float m = r0 * w[off]
                          + r1 * w[off + (size_t)128 * CIN * 9]
                          + r2 * w[off + (size_t)2 * 128 * CIN * 9];
            const int cc = ci >> 4, o = (ci >> 3) & 1, e = ci & 7;
            const size_t dst = (((size_t)(b * NCC + cc)) * 2304
                             + (tap * 128 + co) * 2 + (o ^ sw)) * 8 + e;
            wmix[dst] = f2bf(m);
        }
    }
}

// ---------------------------------------------------------------------------
// MFMA implicit-GEMM conv3x3(pad1) + fused bias/BN/ReLU. v6:
//  - mfma_f32_32x32x16_bf16: 2x FLOP per operand byte -> MFMA-bound tap loop
//  - block tile M=128co x N=512px (4 rows), 8 waves = 2(M) x 4(N),
//    wave tile 64co x 128px (2mf x 4nf) -> 0.75KB LDS read per MFMA
//  - 16-ci K-chunks; input AND weights double-buffered via global_load_lds
//    (123,648B LDS); tap loop is pure ds_read+MFMA, one barrier per chunk
//  - halo cols + OOB rows pre-zeroed once, never re-staged
//  - 512 blocks (XCD-chunked), conv2 stores straight from C/D regs (each
//    32-lane row = one full 128B line), conv1 via padded-LDS transpose
// ---------------------------------------------------------------------------
template <int CIN, bool TO_BF16>
__global__ __launch_bounds__(512, 2)
void conv_mfma5_kernel(const ushort* __restrict__ xT, const ushort* __restrict__ wmix,
                       const float* __restrict__ scsh,
                       float* __restrict__ outf, ushort* __restrict__ outh) {
    constexpr int NCC = CIN / 16;
    constexpr int IBUF = 24960;          // 6 rows * 260 granules * 16B
    constexpr int WOFF = 2 * IBUF;       // 49920
    constexpr int WBUF = 36864;          // 2304 granules * 16B
    __shared__ __align__(16) char smem[123648];

    const int L = ((blockIdx.x & 7) << 6) | (blockIdx.x >> 3);  // 64 per XCD
    const int b = L >> 5;
    const int rt = L & 31;               // output rows rt*4 .. rt*4+3

    const int tid = threadIdx.x;
    const int lane = tid & 63, wid = tid >> 6;
    const int wm = wid >> 2, wn = wid & 3;       // 2(M) x 4(N=row)
    const int l31 = lane & 31, lhi = lane >> 5;

    f32x16 acc[2][4];
#pragma unroll
    for (int i = 0; i < 2; ++i)
#pragma unroll
        for (int j = 0; j < 4; ++j)
#pragma unroll
            for (int r = 0; r < 16; ++r) acc[i][j][r] = 0.f;

    const ushort* inb = xT + (size_t)b * 128 * NCC * 2048;
    const ushort* wmb = wmix + (size_t)b * NCC * 18432;

    // ---- stage chunk cc into dbuf bufi: 24 input + 36 weight 1KB gllds ----
    auto stage = [&](int bufi, int cc) {
        const ushort* wsrc = wmb + (size_t)cc * 18432;
        for (int j = wid; j < 60; j += 8) {
            if (j < 24) {
                const int r = j >> 2, i = j & 3;
                const int hg = rt * 4 - 1 + r;
                if ((unsigned)hg < 128u) {
                    const int q = i * 64 + lane;
                    const int cm1 = q >> 1;
                    const int so = (q & 1) ^ (((cm1 + 1) >> 2) & 1);
                    const ushort* src = inb + ((size_t)(hg * NCC + cc)) * 2048 + cm1 * 16 + so * 8;
                    __builtin_amdgcn_global_load_lds(
                        (const __attribute__((address_space(1))) void*)src,
                        (__attribute__((address_space(3))) void*)(smem + bufi * IBUF + (r * 260 + 2 + i * 64) * 16),
                        16, 0, 0);
                }
            } else {
                const int k = j - 24;
                const ushort* src = wsrc + k * 512 + lane * 8;
                __builtin_amdgcn_global_load_lds(
                    (const __attribute__((address_space(1))) void*)src,
                    (__attribute__((address_space(3))) void*)(smem + WOFF + bufi * WBUF + k * 1024),
                    16, 0, 0);
            }
        }
    };

    // ---- all 9 taps of a chunk: pure ds_read + MFMA ----
    auto taps = [&](int bufi) {
        const char* ldsI = smem + bufi * IBUF;
        const char* ldsW = smem + WOFF + bufi * WBUF;
#pragma unroll
        for (int tap = 0; tap < 9; ++tap) {
            const int dy = tap / 3, dx = tap - dy * 3;
            bf16x8 af[2];
#pragma unroll
            for (int mf = 0; mf < 2; ++mf) {
                const int co = wm * 64 + mf * 32 + l31;
                const int g = (tap * 128 + co) * 2 + (lhi ^ ((co >> 2) & 1));
                af[mf] = *(const bf16x8*)(ldsW + g * 16);
            }
#pragma unroll
            for (int nf = 0; nf < 4; ++nf) {
                const int col = nf * 32 + l31 + dx;
                const int g = (wn + dy) * 260 + col * 2 + (lhi ^ ((col >> 2) & 1));
                const bf16x8 bv = *(const bf16x8*)(ldsI + g * 16);
#pragma unroll
                for (int mf = 0; mf < 2; ++mf)
                    acc[mf][nf] = __builtin_amdgcn_mfma_f32_32x32x16_bf16(
                        af[mf], bv, acc[mf][nf], 0, 0, 0);
            }
        }
    };

    // ---- one-time zeroing: halo cols (0,129) all rows/bufs; OOB rows ----
    if (tid < 48) {
        const int bi = tid & 1, idx = tid >> 1;
        const int r = idx >> 2, e = idx & 3;
        const int rem = (e < 2) ? e : 256 + e;   // granules 0,1,258,259
        *(f32x4*)(smem + bi * IBUF + (r * 260 + rem) * 16) = f32x4{0.f, 0.f, 0.f, 0.f};
    }
    if (rt == 0 || rt == 31) {
        const int r = (rt == 0) ? 0 : 5;
        for (int g = tid; g < 520; g += 512) {
            const int bi = (g >= 260) ? 1 : 0, gr = g - bi * 260;
            *(f32x4*)(smem + bi * IBUF + (r * 260 + gr) * 16) = f32x4{0.f, 0.f, 0.f, 0.f};
        }
    }

    stage(0, 0);
    asm volatile("s_waitcnt vmcnt(0)" ::: "memory");
    __syncthreads();

    for (int cc = 0; cc < NCC; ++cc) {
        if (cc + 1 < NCC) stage((cc & 1) ^ 1, cc + 1);   // async, drains at barrier
        __builtin_amdgcn_sched_barrier(0);
        taps(cc & 1);                                    // pure LDS + MFMA
        __syncthreads();
    }

    // ---- epilogue: y = relu(acc*sc + sh) ----
    if constexpr (!TO_BF16) {
        // fp32 NCHW direct store: each (q,s,nf) = 32 consecutive floats/row
#pragma unroll
        for (int mf = 0; mf < 2; ++mf) {
            const int cob = wm * 64 + mf * 32 + 4 * lhi;
            f32x4 sc[4], sh[4];
#pragma unroll
            for (int q = 0; q < 4; ++q) {
                sc[q] = *(const f32x4*)&scsh[cob + 8 * q];
                sh[q] = *(const f32x4*)&scsh[128 + cob + 8 * q];
            }
#pragma unroll
            for (int nf = 0; nf < 4; ++nf) {
                const size_t pbase = (size_t)(rt * 4 + wn) * 128 + nf * 32 + l31;
#pragma unroll
                for (int q = 0; q < 4; ++q)
#pragma unroll
                    for (int s = 0; s < 4; ++s) {
                        float y = fmaf(acc[mf][nf][q * 4 + s], sc[q][s], sh[q][s]);
                        y = y > 0.f ? y : 0.f;
                        outf[((size_t)(b * 128 + cob + 8 * q + s)) * 16384 + pbase] = y;
                    }
            }
        }
    } else {
        // bf16 16ci-planar hT via padded-LDS transpose, 2 passes of 2 rows
        ushort* sf = (ushort*)smem;                      // [256 px][136]
#pragma unroll
        for (int p = 0; p < 2; ++p) {
            if ((wn >> 1) == p) {
                const int lr = wn & 1;
#pragma unroll
                for (int mf = 0; mf < 2; ++mf)
#pragma unroll
                    for (int q = 0; q < 4; ++q) {
                        const int co4 = wm * 64 + mf * 32 + 8 * q + 4 * lhi;
                        const f32x4 sc = *(const f32x4*)&scsh[co4];
                        const f32x4 sh = *(const f32x4*)&scsh[128 + co4];
#pragma unroll
                        for (int nf = 0; nf < 4; ++nf) {
                            const int px = lr * 128 + nf * 32 + l31;
                            float v[4];
#pragma unroll
                            for (int s = 0; s < 4; ++s) {
                                float y = fmaf(acc[mf][nf][q * 4 + s], sc[s], sh[s]);
                                v[s] = y > 0.f ? y : 0.f;
                            }
                            uint2 pk;
                            pk.x = (uint)f2bf(v[0]) | ((uint)f2bf(v[1]) << 16);
                            pk.y = (uint)f2bf(v[2]) | ((uint)f2bf(v[3]) << 16);
                            *(uint2*)&sf[px * 136 + co4] = pk;
                        }
                    }
            }
            __syncthreads();
#pragma unroll
            for (int it = 0; it < 4; ++it) {
                const int id = it * 512 + tid;           // [lr2][cc8][w128]
                const int lr = id >> 10, cc = (id >> 7) & 7, w = id & 127;
                const uint4 v0 = *(const uint4*)&sf[(lr * 128 + w) * 136 + cc * 16];
                const uint4 v1 = *(const uint4*)&sf[(lr * 128 + w) * 136 + cc * 16 + 8];
                ushort* dst = outh + (((size_t)(b * 128 + rt * 4 + 2 * p + lr)) * 8 + cc) * 2048 + w * 16;
                *(uint4*)dst = v0;
                *(uint4*)(dst + 8) = v1;
            }
            if (p == 0) __syncthreads();
        }
    }
}

// ---------------------------------------------------------------------------
extern "C" void kernel_launch(void* const* d_in, const int* in_sizes, int n_in,
                              void* d_out, int out_size, void* d_ws, size_t ws_size,
                              hipStream_t stream) {
    const float* x     = (const float*)d_in[0];
    const float* w1    = (const float*)d_in[1];
    const float* b1    = (const float*)d_in[2];
    const float* fc1_w = (const float*)d_in[3];
    const float* fc1_b = (const float*)d_in[4];
    const float* bn1g  = (const float*)d_in[5];
    const float* bn1b  = (const float*)d_in[6];
    const float* bn1m  = (const float*)d_in[7];
    const float* bn1v  = (const float*)d_in[8];
    const float* w2    = (const float*)d_in[9];
    const float* b2    = (const float*)d_in[10];
    const float* fc2_w = (const float*)d_in[11];
    const float* fc2_b = (const float*)d_in[12];
    const float* bn2g  = (const float*)d_in[13];
    const float* bn2b  = (const float*)d_in[14];
    const float* bn2m  = (const float*)d_in[15];
    const float* bn2v  = (const float*)d_in[16];

    float* out = (float*)d_out;
    char* ws = (char*)d_ws;

    // workspace layout (bytes)
    ushort* hT    = (ushort*)(ws + 0);            //  67,108,864
    ushort* xT    = (ushort*)(ws + 67108864);     //  33,554,432
    ushort* wmix1 = (ushort*)(ws + 100663296);    //   2,359,296
    ushort* wmix2 = (ushort*)(ws + 103022592);    //   4,718,592
    float*  pool1 = (float*) (ws + 107741184);    //       4,096
    float*  pool2 = (float*) (ws + 107745280);    //       8,192
    float*  scsh1 = (float*) (ws + 107753472);    //       1,024
    float*  scsh2 = (float*) (ws + 107754496);    //       1,024

    hipMemsetAsync(pool1, 0, 4096, stream);
    hipMemsetAsync(pool2, 0, 8192, stream);

    scsh_kernel<<<1, 256, 0, stream>>>(b1, bn1g, bn1b, bn1m, bn1v,
                                       b2, bn2g, bn2b, bn2m, bn2v, scsh1, scsh2);

    // ---- layer 1 ----
    xprep_kernel<<<dim3(256, 16), 256, 0, stream>>>(x, xT, pool1);
    mix_route_kernel<64><<<128, 256, 0, stream>>>(w1, pool1, fc1_w, fc1_b, wmix1);
    conv_mfma5_kernel<64, true><<<512, 512, 0, stream>>>(
        xT, wmix1, scsh1, nullptr, hT);

    // ---- layer 2 ----
    pool2h_kernel<<<dim3(16, 32), 256, 0, stream>>>(hT, pool2);
    mix_route_kernel<128><<<128, 256, 0, stream>>>(w2, pool2, fc2_w, fc2_b, wmix2);
    conv_mfma5_kernel<128, false><<<512, 512, 0, stream>>>(
        hT, wmix2, scsh2, out, nullptr);
}